// Round 30
// baseline (127806.616 us; speedup 1.0000x reference)
//
#include <hip/hip_runtime.h>
#include <hip/hip_cooperative_groups.h>

namespace cg = cooperative_groups;

constexpr int kNB = 64;    // batch
constexpr int kNS = 512;   // encoder sequence length
constexpr int kNH = 512;   // hidden dim
constexpr int kNG = 2048;  // 4*kNH gate rows
constexpr int kNT = 512;   // decoder steps

__device__ __forceinline__ float chpn_sigmoid(float x) {
    return 1.0f / (1.0f + __expf(-x));
}
__device__ __forceinline__ float chpn_tanh(float x) {
    x = fmaxf(fminf(x, 15.0f), -15.0f);
    float e = __expf(2.0f * x);
    return (e - 1.0f) / (e + 1.0f);
}

// ------- init: zero h0/c, fused biases, transposed W_query ---------------
__global__ void ConvexHullPointerNetwork_57303453663418_kernel(
    const float* ebih, const float* ebhh,
    const float* dbih, const float* dbhh,
    const float* wq,
    float* enc_b, float* dec_b, float* wqT, float* h0c)
{
    int i = blockIdx.x * 256 + threadIdx.x;
    if (i < kNG) { enc_b[i] = ebih[i] + ebhh[i]; dec_b[i] = dbih[i] + dbhh[i]; }
    if (i < 2 * kNB * kNH) h0c[i] = 0.0f;
    if (i < kNH * kNH) {
        int r = i >> 9, c = i & 511;
        wqT[c * kNH + r] = wq[i];
    }
}

// ======= cooperative encoder loop: 256 blocks x 512 thr (2 j per block) ==
__global__ __launch_bounds__(512) void chpn_enc_loop(
    const float* __restrict__ inputs, const float* __restrict__ wih,
    const float* __restrict__ whh, const float* __restrict__ bias,
    float* __restrict__ h0, float* __restrict__ h1,
    float* __restrict__ c_st, float* __restrict__ enc_outs)
{
    cg::grid_group grid = cg::this_grid();
    __shared__ float tile[64][65];
    __shared__ float gate_lds[2][4][64];
    const int tid = threadIdx.x;
    const int bb = tid & 63, gg = (tid >> 6) & 3, jj = tid >> 8;
    const int j = (int)blockIdx.x * 2 + jj;
    const int r = gg * kNH + j;
    const float* w = whh + (size_t)r * kNH;
    const float wx0 = wih[r * 2], wx1 = wih[r * 2 + 1], bj = bias[r];

    for (int t = 0; t < kNS; ++t) {
        const float* hs = (t & 1) ? h1 : h0;
        float* hd = (t & 1) ? h0 : h1;
        float acc = 0.f;
        for (int ch = 0; ch < 8; ++ch) {
            const int k0 = ch * 64;
            for (int i = 0; i < 8; ++i) {
                int e = tid + i * 512; int kk = e & 63, b2 = e >> 6;
                tile[kk][b2] = hs[b2 * kNH + k0 + kk];
            }
            __syncthreads();
            #pragma unroll
            for (int kk = 0; kk < 64; ++kk)
                acc = fmaf(tile[kk][bb], w[k0 + kk], acc);
            __syncthreads();
        }
        float x0 = inputs[(bb * kNS + t) * 2 + 0];
        float x1 = inputs[(bb * kNS + t) * 2 + 1];
        acc += bj + wx0 * x0 + wx1 * x1;
        gate_lds[jj][gg][bb] = acc;
        __syncthreads();
        if (tid < 128) {
            int j2 = (int)blockIdx.x * 2 + (tid >> 6), b = tid & 63;
            int jl = tid >> 6;
            float gi = gate_lds[jl][0][b], gf = gate_lds[jl][1][b];
            float gc = gate_lds[jl][2][b], go = gate_lds[jl][3][b];
            float cc = chpn_sigmoid(gf) * c_st[b * kNH + j2] +
                       chpn_sigmoid(gi) * chpn_tanh(gc);
            float hh = chpn_sigmoid(go) * chpn_tanh(cc);
            c_st[b * kNH + j2] = cc;
            hd[b * kNH + j2] = hh;
            enc_outs[((size_t)b * kNS + t) * kNH + j2] = hh;
        }
        __syncthreads();
        grid.sync();
    }
}

// ======= cooperative decoder loop: 256 blocks x 512 thr ==================
__global__ __launch_bounds__(512) void chpn_dec_loop(
    const float* __restrict__ wih, const float* __restrict__ whh,
    const float* __restrict__ bias, const float* __restrict__ wqT,
    const float* __restrict__ vvec,
    const float* __restrict__ keysT, const float* __restrict__ enc_outs,
    float* __restrict__ h0, float* __restrict__ h1, float* __restrict__ c_st,
    float* __restrict__ query, float* __restrict__ ctx_num,
    float* __restrict__ denom, float* __restrict__ out)
{
    cg::grid_group grid = cg::this_grid();
    __shared__ float tile[64][65];
    __shared__ float gate_lds[2][4][64];
    __shared__ float invd[64];
    __shared__ float qpart[4][128];
    __shared__ float ql[kNH], vl[kNH];
    __shared__ float part[4][128];
    __shared__ float el[128];

    const int tid = threadIdx.x;
    const int bid = (int)blockIdx.x;
    const int bb = tid & 63, gg = (tid >> 6) & 3, jj = tid >> 8;
    const int j = bid * 2 + jj;
    const int rr = gg * kNH + j;
    const float* wih_r = wih + (size_t)rr * kNH;
    const float* whh_r = whh + (size_t)rr * kNH;
    const float bias_r = bias[rr];
    const int qb = bid >> 2, qc = bid & 3;   // query/score: (b, 128-chunk)
    const int s0 = qc * 128;

    for (int t = 0; t < kNT; ++t) {
        const int first = (t == 0);
        const float* hs = (t & 1) ? h1 : h0;
        float* hd = (t & 1) ? h0 : h1;

        // ------------- phase CELL (block = 2 j's) ------------------------
        if (tid < 64) invd[tid] = first ? 0.0f : (1.0f / denom[tid]);
        __syncthreads();
        float acc = 0.f;
        for (int ch = 0; ch < 8; ++ch) {      // x half (context)
            const int k0 = ch * 64;
            for (int i = 0; i < 8; ++i) {
                int e = tid + i * 512; int kk = e & 63, b2 = e >> 6;
                tile[kk][b2] = first ? 0.0f
                             : ctx_num[b2 * kNH + k0 + kk] * invd[b2];
            }
            __syncthreads();
            #pragma unroll
            for (int kk = 0; kk < 64; ++kk)
                acc = fmaf(tile[kk][bb], wih_r[k0 + kk], acc);
            __syncthreads();
        }
        for (int ch = 0; ch < 8; ++ch) {      // h half
            const int k0 = ch * 64;
            for (int i = 0; i < 8; ++i) {
                int e = tid + i * 512; int kk = e & 63, b2 = e >> 6;
                tile[kk][b2] = hs[b2 * kNH + k0 + kk];
            }
            __syncthreads();
            #pragma unroll
            for (int kk = 0; kk < 64; ++kk)
                acc = fmaf(tile[kk][bb], whh_r[k0 + kk], acc);
            __syncthreads();
        }
        acc += bias_r;
        gate_lds[jj][gg][bb] = acc;
        __syncthreads();
        if (tid < 128) {
            int j2 = bid * 2 + (tid >> 6), b = tid & 63;
            int jl = tid >> 6;
            float gi = gate_lds[jl][0][b], gf = gate_lds[jl][1][b];
            float gc = gate_lds[jl][2][b], go = gate_lds[jl][3][b];
            float cc = chpn_sigmoid(gf) * c_st[b * kNH + j2] +
                       chpn_sigmoid(gi) * chpn_tanh(gc);
            float hh = chpn_sigmoid(go) * chpn_tanh(cc);
            c_st[b * kNH + j2] = cc;
            hd[b * kNH + j2] = hh;
        }
        __syncthreads();
        grid.sync();

        // ------------- phase QUERY (block = b, 128-h chunk) --------------
        {
            int h = qc * 128 + (tid & 127);
            int jq = tid >> 7;                // 4 j-quarters of 128
            float qa = 0.f;
            const float* wcol = wqT + h;
            const float* hb = hd + qb * kNH;
            #pragma unroll 8
            for (int jx = jq * 128; jx < jq * 128 + 128; ++jx)
                qa = fmaf(hb[jx], wcol[(size_t)jx * kNH], qa);
            qpart[jq][tid & 127] = qa;
            __syncthreads();
            if (tid < 128) {
                float q = qpart[0][tid] + qpart[1][tid] +
                          qpart[2][tid] + qpart[3][tid];
                query[qb * kNH + qc * 128 + tid] = q;
                ctx_num[qb * kNH + qc * 128 + tid] = 0.0f;
                if (qc == 0 && tid == 0) denom[qb] = 0.0f;
            }
            __syncthreads();
        }
        grid.sync();

        // ------------- phase SCORE + CTX (block = b, 128-s chunk) --------
        {
            ql[tid] = query[qb * kNH + tid];
            vl[tid] = vvec[tid];
            __syncthreads();

            int s = tid & 127, hq = tid >> 7; // 4 h-groups of 128
            float sa = 0.f;
            const float* kp = keysT + (size_t)qb * kNH * kNS + s0 + s;
            const int h0i = hq * 128;
            #pragma unroll 4
            for (int h = h0i; h < h0i + 128; ++h) {
                float kv = kp[(size_t)h * kNS];
                sa = fmaf(vl[h], chpn_tanh(ql[h] + kv), sa);
            }
            part[hq][s] = sa;
            __syncthreads();

            if (tid < 128) {
                float scv = part[0][tid] + part[1][tid] +
                            part[2][tid] + part[3][tid];
                out[((size_t)qb * kNT + t) * kNS + s0 + tid] = scv;
                float e = __expf(scv);        // scores tiny; no max-sub
                el[tid] = e;
                float wsum = e;
                #pragma unroll
                for (int off = 32; off > 0; off >>= 1)
                    wsum += __shfl_down(wsum, off);
                if ((tid & 63) == 0) atomicAdd(&denom[qb], wsum);
            }
            __syncthreads();

            float a = 0.f;
            const float* ep = enc_outs + ((size_t)qb * kNS + s0) * kNH + tid;
            #pragma unroll 4
            for (int ss = 0; ss < 128; ++ss)
                a = fmaf(el[ss], ep[(size_t)ss * kNH], a);
            atomicAdd(&ctx_num[qb * kNH + tid], a);
            __syncthreads();
        }
        grid.sync();
    }
}

// ======= fallback per-step kernels (R28, proven) =========================
__global__ __launch_bounds__(256) void fb_enc_cell(
    const float* __restrict__ inputs, const float* __restrict__ wih,
    const float* __restrict__ whh, const float* __restrict__ bias,
    const float* __restrict__ h_src, float* __restrict__ h_dst,
    float* __restrict__ c_st, float* __restrict__ enc_outs, int t)
{
    __shared__ float tile[64][65];
    __shared__ float gate_lds[4][64];
    const int tid = threadIdx.x;
    const int bb = tid & 63, gg = tid >> 6;
    const int j = (int)blockIdx.x;
    const int r = gg * kNH + j;
    const float* w = whh + (size_t)r * kNH;
    float acc = 0.f;
    for (int ch = 0; ch < 8; ++ch) {
        const int k0 = ch * 64;
        for (int i = 0; i < 16; ++i) {
            int e = tid + i * 256; int kk = e & 63, b2 = e >> 6;
            tile[kk][b2] = h_src[b2 * kNH + k0 + kk];
        }
        __syncthreads();
        #pragma unroll
        for (int kk = 0; kk < 64; ++kk)
            acc = fmaf(tile[kk][bb], w[k0 + kk], acc);
        __syncthreads();
    }
    float x0 = inputs[(bb * kNS + t) * 2 + 0];
    float x1 = inputs[(bb * kNS + t) * 2 + 1];
    acc += bias[r] + wih[r * 2] * x0 + wih[r * 2 + 1] * x1;
    gate_lds[gg][bb] = acc;
    __syncthreads();
    if (tid < 64) {
        float gi = gate_lds[0][tid], gf = gate_lds[1][tid];
        float gc = gate_lds[2][tid], go = gate_lds[3][tid];
        float cc = chpn_sigmoid(gf) * c_st[tid * kNH + j] + chpn_sigmoid(gi) * chpn_tanh(gc);
        float hh = chpn_sigmoid(go) * chpn_tanh(cc);
        c_st[tid * kNH + j] = cc;
        h_dst[tid * kNH + j] = hh;
        enc_outs[((size_t)tid * kNS + t) * kNH + j] = hh;
    }
}

__global__ __launch_bounds__(256) void fb_dec_cell(
    const float* __restrict__ wih, const float* __restrict__ whh,
    const float* __restrict__ bias,
    const float* __restrict__ h_src, float* __restrict__ h_dst,
    float* __restrict__ c_st,
    const float* __restrict__ ctx_num, const float* __restrict__ denom,
    int first)
{
    __shared__ float tile[64][65];
    __shared__ float gate_lds[4][64];
    __shared__ float invd[64];
    const int tid = threadIdx.x;
    const int bb = tid & 63, gg = tid >> 6;
    const int j = (int)blockIdx.x;
    if (tid < 64) invd[tid] = first ? 0.0f : (1.0f / denom[tid]);
    __syncthreads();
    const int r = gg * kNH + j;
    float acc = 0.f;
    {
        const float* w = wih + (size_t)r * kNH;
        for (int ch = 0; ch < 8; ++ch) {
            const int k0 = ch * 64;
            for (int i = 0; i < 16; ++i) {
                int e = tid + i * 256; int kk = e & 63, b2 = e >> 6;
                tile[kk][b2] = first ? 0.0f : ctx_num[b2 * kNH + k0 + kk] * invd[b2];
            }
            __syncthreads();
            #pragma unroll
            for (int kk = 0; kk < 64; ++kk)
                acc = fmaf(tile[kk][bb], w[k0 + kk], acc);
            __syncthreads();
        }
    }
    {
        const float* w = whh + (size_t)r * kNH;
        for (int ch = 0; ch < 8; ++ch) {
            const int k0 = ch * 64;
            for (int i = 0; i < 16; ++i) {
                int e = tid + i * 256; int kk = e & 63, b2 = e >> 6;
                tile[kk][b2] = h_src[b2 * kNH + k0 + kk];
            }
            __syncthreads();
            #pragma unroll
            for (int kk = 0; kk < 64; ++kk)
                acc = fmaf(tile[kk][bb], w[k0 + kk], acc);
            __syncthreads();
        }
    }
    acc += bias[r];
    gate_lds[gg][bb] = acc;
    __syncthreads();
    if (tid < 64) {
        float gi = gate_lds[0][tid], gf = gate_lds[1][tid];
        float gc = gate_lds[2][tid], go = gate_lds[3][tid];
        float cc = chpn_sigmoid(gf) * c_st[tid * kNH + j] + chpn_sigmoid(gi) * chpn_tanh(gc);
        float hh = chpn_sigmoid(go) * chpn_tanh(cc);
        c_st[tid * kNH + j] = cc;
        h_dst[tid * kNH + j] = hh;
    }
}

__global__ __launch_bounds__(256) void fb_query(
    const float* __restrict__ wqT, const float* __restrict__ h_src,
    float* __restrict__ query, float* __restrict__ ctx_num,
    float* __restrict__ denom)
{
    __shared__ float hl[kNH];
    __shared__ float partq[256];
    int bid = blockIdx.x;
    int bb = bid >> 2, hc = bid & 3;
    int tid = threadIdx.x;
    hl[tid] = h_src[bb * kNH + tid];
    hl[tid + 256] = h_src[bb * kNH + tid + 256];
    __syncthreads();
    int h = hc * 128 + (tid & 127);
    int jh = tid >> 7;
    float acc = 0.f;
    const float* wcol = wqT + h;
    #pragma unroll 8
    for (int j = jh * 256; j < jh * 256 + 256; ++j)
        acc = fmaf(hl[j], wcol[(size_t)j * kNH], acc);
    partq[tid] = acc;
    __syncthreads();
    if (tid < 128) {
        float q = partq[tid] + partq[tid + 128];
        query[bb * kNH + h] = q;
        ctx_num[bb * kNH + h] = 0.0f;
        if (hc == 0 && tid == 0) denom[bb] = 0.0f;
    }
}

__global__ __launch_bounds__(1024) void fb_score_ctx(
    const float* __restrict__ keysT, const float* __restrict__ enc_outs,
    const float* __restrict__ query, const float* __restrict__ vvec,
    float* __restrict__ ctx_num, float* __restrict__ denom,
    float* __restrict__ out, int t)
{
    __shared__ float ql[kNH], vl[kNH];
    __shared__ float part[16][64];
    __shared__ float el[64];
    int bid = blockIdx.x;
    int bb = bid >> 3, sc = bid & 7;
    int s0 = sc * 64;
    int tid = threadIdx.x;
    int s = tid & 63, hq = tid >> 6;
    if (tid < kNH) { ql[tid] = query[bb * kNH + tid]; vl[tid] = vvec[tid]; }
    __syncthreads();
    float acc = 0.f;
    const float* kp = keysT + (size_t)bb * kNH * kNS + s0 + s;
    const int h0 = hq * 32;
    #pragma unroll 4
    for (int h = h0; h < h0 + 32; ++h) {
        float kv = kp[(size_t)h * kNS];
        acc = fmaf(vl[h], chpn_tanh(ql[h] + kv), acc);
    }
    part[hq][s] = acc;
    __syncthreads();
    if (tid < 64) {
        float scv = 0.f;
        #pragma unroll
        for (int q = 0; q < 16; ++q) scv += part[q][tid];
        out[((size_t)bb * kNT + t) * kNS + s0 + tid] = scv;
        float e = __expf(scv);
        el[tid] = e;
        float wsum = e;
        #pragma unroll
        for (int off = 32; off > 0; off >>= 1) wsum += __shfl_down(wsum, off);
        if (tid == 0) atomicAdd(&denom[bb], wsum);
    }
    __syncthreads();
    int j = tid & 511, sh = tid >> 9;
    float a = 0.f;
    const float* ep = enc_outs + ((size_t)bb * kNS + s0 + sh * 32) * kNH + j;
    #pragma unroll 4
    for (int ss = 0; ss < 32; ++ss)
        a = fmaf(el[sh * 32 + ss], ep[(size_t)ss * kNH], a);
    atomicAdd(&ctx_num[bb * kNH + j], a);
}

// -------- keysT[b][h][s] GEMM (f32) --------------------------------------
__global__ __launch_bounds__(256) void chpn_keys_gemm(
    const float* __restrict__ enc_outs, const float* __restrict__ wk,
    float* __restrict__ keysT)
{
    int bid = blockIdx.x;
    int bb = bid >> 6, ht = (bid >> 3) & 7, st = bid & 7;
    __shared__ float asb[32][66];
    __shared__ float bsb[32][66];
    int tid = threadIdx.x;
    int tx = tid & 15, ty = tid >> 4;
    float acc[4][4] = {};
    for (int j0 = 0; j0 < kNH; j0 += 32) {
        for (int i = 0; i < 8; ++i) {
            int e = tid + i * 256;
            int j = e & 31, s = e >> 5;
            asb[j][s] = enc_outs[((size_t)bb * kNS + st * 64 + s) * kNH + j0 + j];
            bsb[j][s] = wk[(size_t)(ht * 64 + s) * kNH + j0 + j];
        }
        __syncthreads();
        #pragma unroll 8
        for (int j = 0; j < 32; ++j) {
            float a0 = asb[j][tx*4], a1 = asb[j][tx*4+1], a2 = asb[j][tx*4+2], a3 = asb[j][tx*4+3];
            float b0 = bsb[j][ty*4], b1 = bsb[j][ty*4+1], b2 = bsb[j][ty*4+2], b3 = bsb[j][ty*4+3];
            acc[0][0] = fmaf(b0,a0,acc[0][0]); acc[0][1] = fmaf(b0,a1,acc[0][1]);
            acc[0][2] = fmaf(b0,a2,acc[0][2]); acc[0][3] = fmaf(b0,a3,acc[0][3]);
            acc[1][0] = fmaf(b1,a0,acc[1][0]); acc[1][1] = fmaf(b1,a1,acc[1][1]);
            acc[1][2] = fmaf(b1,a2,acc[1][2]); acc[1][3] = fmaf(b1,a3,acc[1][3]);
            acc[2][0] = fmaf(b2,a0,acc[2][0]); acc[2][1] = fmaf(b2,a1,acc[2][1]);
            acc[2][2] = fmaf(b2,a2,acc[2][2]); acc[2][3] = fmaf(b2,a3,acc[2][3]);
            acc[3][0] = fmaf(b3,a0,acc[3][0]); acc[3][1] = fmaf(b3,a1,acc[3][1]);
            acc[3][2] = fmaf(b3,a2,acc[3][2]); acc[3][3] = fmaf(b3,a3,acc[3][3]);
        }
        __syncthreads();
    }
    for (int i = 0; i < 4; ++i)
        for (int k = 0; k < 4; ++k)
            keysT[((size_t)bb * kNH + ht * 64 + ty * 4 + i) * kNS + st * 64 + tx * 4 + k] =
                acc[i][k];
}

extern "C" void kernel_launch(void* const* d_in, const int* in_sizes, int n_in,
                              void* d_out, int out_size, void* d_ws, size_t ws_size,
                              hipStream_t stream) {
    const float* inputs = (const float*)d_in[0];
    const float* e_wih  = (const float*)d_in[1];
    const float* e_whh  = (const float*)d_in[2];
    const float* e_bih  = (const float*)d_in[3];
    const float* e_bhh  = (const float*)d_in[4];
    const float* d_wih  = (const float*)d_in[5];
    const float* d_whh  = (const float*)d_in[6];
    const float* d_bih  = (const float*)d_in[7];
    const float* d_bhh  = (const float*)d_in[8];
    const float* w_key  = (const float*)d_in[9];
    const float* w_qry  = (const float*)d_in[10];
    const float* v_vec  = (const float*)d_in[11];
    float* out = (float*)d_out;               // f32 output (64 MB)

    float* wsf   = (float*)d_ws;
    float* h0    = wsf;
    float* cst   = h0 + kNB * kNH;
    float* h1    = cst + kNB * kNH;
    float* query = h1 + kNB * kNH;
    float* ctxn  = query + kNB * kNH;
    float* denom = ctxn + kNB * kNH;
    float* encb  = denom + 64;
    float* decb  = encb + kNG;
    float* wqT   = decb + kNG;
    float* keysF = wqT + (size_t)kNH * kNH;
    float* encF  = keysF + (size_t)kNB * kNH * kNS;

    ConvexHullPointerNetwork_57303453663418_kernel<<<1024, 256, 0, stream>>>(
        e_bih, e_bhh, d_bih, d_bhh, w_qry, encb, decb, wqT, h0);

    {   // encoder loop (cooperative; fallback to per-step on enqueue error)
        void* args[] = { (void*)&inputs, (void*)&e_wih, (void*)&e_whh,
                         (void*)&encb, (void*)&h0, (void*)&h1,
                         (void*)&cst, (void*)&encF };
        hipError_t rc = hipLaunchCooperativeKernel((const void*)chpn_enc_loop,
                                                   dim3(256), dim3(512),
                                                   args, 0, stream);
        if (rc != hipSuccess) {
            (void)hipGetLastError();
            for (int t = 0; t < kNS; ++t) {
                float* hs = (t & 1) ? h1 : h0;
                float* hd = (t & 1) ? h0 : h1;
                fb_enc_cell<<<512, 256, 0, stream>>>(inputs, e_wih, e_whh, encb,
                                                     hs, hd, cst, encF, t);
            }
        }
    }

    chpn_keys_gemm<<<4096, 256, 0, stream>>>(encF, w_key, keysF);

    {   // decoder loop (cooperative; fallback on enqueue error)
        void* args[] = { (void*)&d_wih, (void*)&d_whh, (void*)&decb,
                         (void*)&wqT, (void*)&v_vec, (void*)&keysF,
                         (void*)&encF, (void*)&h0, (void*)&h1, (void*)&cst,
                         (void*)&query, (void*)&ctxn, (void*)&denom,
                         (void*)&out };
        hipError_t rc = hipLaunchCooperativeKernel((const void*)chpn_dec_loop,
                                                   dim3(256), dim3(512),
                                                   args, 0, stream);
        if (rc != hipSuccess) {
            (void)hipGetLastError();
            for (int t = 0; t < kNT; ++t) {
                float* hs = (t & 1) ? h1 : h0;
                float* hd = (t & 1) ? h0 : h1;
                fb_dec_cell<<<512, 256, 0, stream>>>(d_wih, d_whh, decb,
                                                     hs, hd, cst,
                                                     ctxn, denom, t == 0 ? 1 : 0);
                fb_query<<<256, 256, 0, stream>>>(wqT, hd, query, ctxn, denom);
                fb_score_ctx<<<512, 1024, 0, stream>>>(keysF, encF, query, v_vec,
                                                       ctxn, denom, out, t);
            }
        }
    }
}

// Round 31
// 104881.665 us; speedup vs baseline: 1.2186x; 1.2186x over previous
//
#include <hip/hip_runtime.h>
#include <hip/hip_cooperative_groups.h>

namespace cg = cooperative_groups;

constexpr int kNB = 64;    // batch
constexpr int kNS = 512;   // encoder sequence length
constexpr int kNH = 512;   // hidden dim
constexpr int kNG = 2048;  // 4*kNH gate rows
constexpr int kNT = 512;   // decoder steps

typedef _Float16 chpn_f16;

__device__ __forceinline__ float chpn_sigmoid(float x) {
    return 1.0f / (1.0f + __expf(-x));
}
__device__ __forceinline__ float chpn_tanh(float x) {
    x = fmaxf(fminf(x, 15.0f), -15.0f);
    float e = __expf(2.0f * x);
    return (e - 1.0f) / (e + 1.0f);
}

// ------- init: zero h0/c, fused biases, transposed W_query ---------------
__global__ void ConvexHullPointerNetwork_57303453663418_kernel(
    const float* ebih, const float* ebhh,
    const float* dbih, const float* dbhh,
    const float* wq,
    float* enc_b, float* dec_b, float* wqT, float* h0c)
{
    int i = blockIdx.x * 256 + threadIdx.x;
    if (i < kNG) { enc_b[i] = ebih[i] + ebhh[i]; dec_b[i] = dbih[i] + dbhh[i]; }
    if (i < 2 * kNB * kNH) h0c[i] = 0.0f;
    if (i < kNH * kNH) {
        int r = i >> 9, c = i & 511;
        wqT[c * kNH + r] = wq[i];
    }
}

// ======= cooperative encoder loop: 256 blocks x 1024 thr (2 j/block) =====
__global__ __launch_bounds__(1024) void chpn_enc_loop(
    const float* __restrict__ inputs, const float* __restrict__ wih,
    const float* __restrict__ whh, const float* __restrict__ bias,
    float* __restrict__ h0, float* __restrict__ h1,
    float* __restrict__ c_st, chpn_f16* __restrict__ enc_outs)
{
    cg::grid_group grid = cg::this_grid();
    __shared__ float tile[64][65];
    __shared__ float ghalf[2][2][4][64];   // [pp][jj][gg][bb]
    __shared__ float gates[2][4][64];      // [jj][gg][bb]
    const int tid = threadIdx.x;
    const int bb = tid & 63, gg = (tid >> 6) & 3;
    const int jj = (tid >> 8) & 1, pp = tid >> 9;
    const int j = (int)blockIdx.x * 2 + jj;
    const int r = gg * kNH + j;
    const float* w = whh + (size_t)r * kNH;
    const float wx0 = wih[r * 2], wx1 = wih[r * 2 + 1], bj = bias[r];

    for (int t = 0; t < kNS; ++t) {
        const float* hs = (t & 1) ? h1 : h0;
        float* hd = (t & 1) ? h0 : h1;
        float acc = 0.f;
        for (int ch = 0; ch < 8; ++ch) {
            const int k0 = ch * 64;
            for (int i = 0; i < 4; ++i) {
                int e = tid + i * 1024; int kk = e & 63, b2 = e >> 6;
                tile[kk][b2] = hs[b2 * kNH + k0 + kk];
            }
            __syncthreads();
            if ((ch >> 2) == pp) {
                #pragma unroll
                for (int kk = 0; kk < 64; ++kk)
                    acc = fmaf(tile[kk][bb], w[k0 + kk], acc);
            }
            __syncthreads();
        }
        if (pp == 0) {
            float x0 = inputs[(bb * kNS + t) * 2 + 0];
            float x1 = inputs[(bb * kNS + t) * 2 + 1];
            acc += bj + wx0 * x0 + wx1 * x1;
        }
        ghalf[pp][jj][gg][bb] = acc;
        __syncthreads();
        if (tid < 512) {
            int b = tid & 63, g = (tid >> 6) & 3, jl = tid >> 8;
            gates[jl][g][b] = ghalf[0][jl][g][b] + ghalf[1][jl][g][b];
        }
        __syncthreads();
        if (tid < 128) {
            int b = tid & 63, jl = tid >> 6;
            int j2 = (int)blockIdx.x * 2 + jl;
            float gi = gates[jl][0][b], gf = gates[jl][1][b];
            float gc = gates[jl][2][b], go = gates[jl][3][b];
            float cc = chpn_sigmoid(gf) * c_st[b * kNH + j2] +
                       chpn_sigmoid(gi) * chpn_tanh(gc);
            float hh = chpn_sigmoid(go) * chpn_tanh(cc);
            c_st[b * kNH + j2] = cc;
            hd[b * kNH + j2] = hh;
            enc_outs[((size_t)b * kNS + t) * kNH + j2] = (chpn_f16)hh;
        }
        __syncthreads();
        grid.sync();
    }
}

// ======= cooperative decoder loop: 256 blocks x 1024 thr =================
__global__ __launch_bounds__(1024) void chpn_dec_loop(
    const float* __restrict__ wih, const float* __restrict__ whh,
    const float* __restrict__ bias, const float* __restrict__ wqT,
    const float* __restrict__ vvec,
    const chpn_f16* __restrict__ keysT, const chpn_f16* __restrict__ enc_outs,
    float* __restrict__ h0, float* __restrict__ h1, float* __restrict__ c_st,
    float* __restrict__ query, float* __restrict__ ctx_num,
    float* __restrict__ denom, float* __restrict__ out)
{
    cg::grid_group grid = cg::this_grid();
    __shared__ float tileA[64][65];        // ctx tile
    __shared__ float tileB[64][65];        // h tile
    __shared__ float ghalf[2][2][4][64];   // [pp][jj][gg][bb]
    __shared__ float gates[2][4][64];
    __shared__ float invd[64];
    __shared__ float qpart[8][128];
    __shared__ float ql[kNH], vl[kNH];
    __shared__ float part[8][128];
    __shared__ float el[128];

    const int tid = threadIdx.x;
    const int bid = (int)blockIdx.x;
    const int bb = tid & 63, gg = (tid >> 6) & 3;
    const int jj = (tid >> 8) & 1, pp = tid >> 9;
    const int j = bid * 2 + jj;
    const int rr = gg * kNH + j;
    const float* wsel = (pp ? whh : wih) + (size_t)rr * kNH;
    const float bias_r = bias[rr];
    const int qb = bid >> 2, qc = bid & 3;   // (b, 128-chunk)
    const int s0 = qc * 128;

    for (int t = 0; t < kNT; ++t) {
        const int first = (t == 0);
        const float* hs = (t & 1) ? h1 : h0;
        float* hd = (t & 1) ? h0 : h1;

        // ------------- phase CELL (block = 2 j; x-dot || h-dot) ----------
        if (tid < 64) invd[tid] = first ? 0.0f : (1.0f / denom[tid]);
        __syncthreads();
        float acc = 0.f;
        for (int ch = 0; ch < 8; ++ch) {
            const int k0 = ch * 64;
            for (int i = 0; i < 4; ++i) {
                int e = tid + i * 1024; int kk = e & 63, b2 = e >> 6;
                tileA[kk][b2] = first ? 0.0f
                              : ctx_num[b2 * kNH + k0 + kk] * invd[b2];
                tileB[kk][b2] = hs[b2 * kNH + k0 + kk];
            }
            __syncthreads();
            const float (*tt)[65] = pp ? tileB : tileA;
            #pragma unroll
            for (int kk = 0; kk < 64; ++kk)
                acc = fmaf(tt[kk][bb], wsel[k0 + kk], acc);
            __syncthreads();
        }
        if (pp == 0) acc += bias_r;
        ghalf[pp][jj][gg][bb] = acc;
        __syncthreads();
        if (tid < 512) {
            int b = tid & 63, g = (tid >> 6) & 3, jl = tid >> 8;
            gates[jl][g][b] = ghalf[0][jl][g][b] + ghalf[1][jl][g][b];
        }
        __syncthreads();
        if (tid < 128) {
            int b = tid & 63, jl = tid >> 6;
            int j2 = bid * 2 + jl;
            float gi = gates[jl][0][b], gf = gates[jl][1][b];
            float gc = gates[jl][2][b], go = gates[jl][3][b];
            float cc = chpn_sigmoid(gf) * c_st[b * kNH + j2] +
                       chpn_sigmoid(gi) * chpn_tanh(gc);
            float hh = chpn_sigmoid(go) * chpn_tanh(cc);
            c_st[b * kNH + j2] = cc;
            hd[b * kNH + j2] = hh;
        }
        __syncthreads();
        grid.sync();

        // ------------- phase QUERY (block = b, 128-h chunk) --------------
        {
            int h = qc * 128 + (tid & 127);
            int jo = tid >> 7;                 // 8 j-eighths of 64
            float qa = 0.f;
            const float* wcol = wqT + h;
            const float* hb = hd + qb * kNH;
            #pragma unroll 8
            for (int jx = jo * 64; jx < jo * 64 + 64; ++jx)
                qa = fmaf(hb[jx], wcol[(size_t)jx * kNH], qa);
            qpart[jo][tid & 127] = qa;
            __syncthreads();
            if (tid < 128) {
                float q = 0.f;
                #pragma unroll
                for (int o = 0; o < 8; ++o) q += qpart[o][tid];
                query[qb * kNH + qc * 128 + tid] = q;
                ctx_num[qb * kNH + qc * 128 + tid] = 0.0f;
                if (qc == 0 && tid == 0) denom[qb] = 0.0f;
            }
            __syncthreads();
        }
        grid.sync();

        // ------------- phase SCORE + CTX (block = b, 128-s chunk) --------
        {
            if (tid < kNH) { ql[tid] = query[qb * kNH + tid]; vl[tid] = vvec[tid]; }
            __syncthreads();

            int s = tid & 127, hq = tid >> 7;  // 8 h-groups of 64
            float sa = 0.f;
            const chpn_f16* kp = keysT + (size_t)qb * kNH * kNS + s0 + s;
            const int h0i = hq * 64;
            #pragma unroll 4
            for (int h = h0i; h < h0i + 64; ++h) {
                float kv = (float)kp[(size_t)h * kNS];
                sa = fmaf(vl[h], chpn_tanh(ql[h] + kv), sa);
            }
            part[hq][s] = sa;
            __syncthreads();

            if (tid < 128) {
                float scv = 0.f;
                #pragma unroll
                for (int o = 0; o < 8; ++o) scv += part[o][tid];
                out[((size_t)qb * kNT + t) * kNS + s0 + tid] = scv;
                float e = __expf(scv);         // scores tiny; no max-sub
                el[tid] = e;
                float wsum = e;
                #pragma unroll
                for (int off = 32; off > 0; off >>= 1)
                    wsum += __shfl_down(wsum, off);
                if ((tid & 63) == 0) atomicAdd(&denom[qb], wsum);
            }
            __syncthreads();

            int jx = tid & 511, sh = tid >> 9;
            float a = 0.f;
            const chpn_f16* ep = enc_outs +
                ((size_t)qb * kNS + s0 + sh * 64) * kNH + jx;
            #pragma unroll 4
            for (int ss = 0; ss < 64; ++ss)
                a = fmaf(el[sh * 64 + ss], (float)ep[(size_t)ss * kNH], a);
            atomicAdd(&ctx_num[qb * kNH + jx], a);
            __syncthreads();
        }
        grid.sync();
    }
}

// -------- keysT[b][h][s] GEMM (fp16 in/out) ------------------------------
__global__ __launch_bounds__(256) void chpn_keys_gemm(
    const chpn_f16* __restrict__ enc_outs, const float* __restrict__ wk,
    chpn_f16* __restrict__ keysT)
{
    int bid = blockIdx.x;
    int bb = bid >> 6, ht = (bid >> 3) & 7, st = bid & 7;
    __shared__ float asb[32][66];
    __shared__ float bsb[32][66];
    int tid = threadIdx.x;
    int tx = tid & 15, ty = tid >> 4;
    float acc[4][4] = {};
    for (int j0 = 0; j0 < kNH; j0 += 32) {
        for (int i = 0; i < 8; ++i) {
            int e = tid + i * 256;
            int j = e & 31, s = e >> 5;
            asb[j][s] = (float)enc_outs[((size_t)bb * kNS + st * 64 + s) * kNH + j0 + j];
            bsb[j][s] = wk[(size_t)(ht * 64 + s) * kNH + j0 + j];
        }
        __syncthreads();
        #pragma unroll 8
        for (int j = 0; j < 32; ++j) {
            float a0 = asb[j][tx*4], a1 = asb[j][tx*4+1], a2 = asb[j][tx*4+2], a3 = asb[j][tx*4+3];
            float b0 = bsb[j][ty*4], b1 = bsb[j][ty*4+1], b2 = bsb[j][ty*4+2], b3 = bsb[j][ty*4+3];
            acc[0][0] = fmaf(b0,a0,acc[0][0]); acc[0][1] = fmaf(b0,a1,acc[0][1]);
            acc[0][2] = fmaf(b0,a2,acc[0][2]); acc[0][3] = fmaf(b0,a3,acc[0][3]);
            acc[1][0] = fmaf(b1,a0,acc[1][0]); acc[1][1] = fmaf(b1,a1,acc[1][1]);
            acc[1][2] = fmaf(b1,a2,acc[1][2]); acc[1][3] = fmaf(b1,a3,acc[1][3]);
            acc[2][0] = fmaf(b2,a0,acc[2][0]); acc[2][1] = fmaf(b2,a1,acc[2][1]);
            acc[2][2] = fmaf(b2,a2,acc[2][2]); acc[2][3] = fmaf(b2,a3,acc[2][3]);
            acc[3][0] = fmaf(b3,a0,acc[3][0]); acc[3][1] = fmaf(b3,a1,acc[3][1]);
            acc[3][2] = fmaf(b3,a2,acc[3][2]); acc[3][3] = fmaf(b3,a3,acc[3][3]);
        }
        __syncthreads();
    }
    for (int i = 0; i < 4; ++i)
        for (int k = 0; k < 4; ++k)
            keysT[((size_t)bb * kNH + ht * 64 + ty * 4 + i) * kNS + st * 64 + tx * 4 + k] =
                (chpn_f16)acc[i][k];
}

// ======= fallback per-step kernels (R28 geometry, fp16 staging) ==========
__global__ __launch_bounds__(256) void fb_enc_cell(
    const float* __restrict__ inputs, const float* __restrict__ wih,
    const float* __restrict__ whh, const float* __restrict__ bias,
    const float* __restrict__ h_src, float* __restrict__ h_dst,
    float* __restrict__ c_st, chpn_f16* __restrict__ enc_outs, int t)
{
    __shared__ float tile[64][65];
    __shared__ float gate_lds[4][64];
    const int tid = threadIdx.x;
    const int bb = tid & 63, gg = tid >> 6;
    const int j = (int)blockIdx.x;
    const int r = gg * kNH + j;
    const float* w = whh + (size_t)r * kNH;
    float acc = 0.f;
    for (int ch = 0; ch < 8; ++ch) {
        const int k0 = ch * 64;
        for (int i = 0; i < 16; ++i) {
            int e = tid + i * 256; int kk = e & 63, b2 = e >> 6;
            tile[kk][b2] = h_src[b2 * kNH + k0 + kk];
        }
        __syncthreads();
        #pragma unroll
        for (int kk = 0; kk < 64; ++kk)
            acc = fmaf(tile[kk][bb], w[k0 + kk], acc);
        __syncthreads();
    }
    float x0 = inputs[(bb * kNS + t) * 2 + 0];
    float x1 = inputs[(bb * kNS + t) * 2 + 1];
    acc += bias[r] + wih[r * 2] * x0 + wih[r * 2 + 1] * x1;
    gate_lds[gg][bb] = acc;
    __syncthreads();
    if (tid < 64) {
        float gi = gate_lds[0][tid], gf = gate_lds[1][tid];
        float gc = gate_lds[2][tid], go = gate_lds[3][tid];
        float cc = chpn_sigmoid(gf) * c_st[tid * kNH + j] + chpn_sigmoid(gi) * chpn_tanh(gc);
        float hh = chpn_sigmoid(go) * chpn_tanh(cc);
        c_st[tid * kNH + j] = cc;
        h_dst[tid * kNH + j] = hh;
        enc_outs[((size_t)tid * kNS + t) * kNH + j] = (chpn_f16)hh;
    }
}

__global__ __launch_bounds__(256) void fb_dec_cell(
    const float* __restrict__ wih, const float* __restrict__ whh,
    const float* __restrict__ bias,
    const float* __restrict__ h_src, float* __restrict__ h_dst,
    float* __restrict__ c_st,
    const float* __restrict__ ctx_num, const float* __restrict__ denom,
    int first)
{
    __shared__ float tile[64][65];
    __shared__ float gate_lds[4][64];
    __shared__ float invd[64];
    const int tid = threadIdx.x;
    const int bb = tid & 63, gg = tid >> 6;
    const int j = (int)blockIdx.x;
    if (tid < 64) invd[tid] = first ? 0.0f : (1.0f / denom[tid]);
    __syncthreads();
    const int r = gg * kNH + j;
    float acc = 0.f;
    {
        const float* w = wih + (size_t)r * kNH;
        for (int ch = 0; ch < 8; ++ch) {
            const int k0 = ch * 64;
            for (int i = 0; i < 16; ++i) {
                int e = tid + i * 256; int kk = e & 63, b2 = e >> 6;
                tile[kk][b2] = first ? 0.0f : ctx_num[b2 * kNH + k0 + kk] * invd[b2];
            }
            __syncthreads();
            #pragma unroll
            for (int kk = 0; kk < 64; ++kk)
                acc = fmaf(tile[kk][bb], w[k0 + kk], acc);
            __syncthreads();
        }
    }
    {
        const float* w = whh + (size_t)r * kNH;
        for (int ch = 0; ch < 8; ++ch) {
            const int k0 = ch * 64;
            for (int i = 0; i < 16; ++i) {
                int e = tid + i * 256; int kk = e & 63, b2 = e >> 6;
                tile[kk][b2] = h_src[b2 * kNH + k0 + kk];
            }
            __syncthreads();
            #pragma unroll
            for (int kk = 0; kk < 64; ++kk)
                acc = fmaf(tile[kk][bb], w[k0 + kk], acc);
            __syncthreads();
        }
    }
    acc += bias[r];
    gate_lds[gg][bb] = acc;
    __syncthreads();
    if (tid < 64) {
        float gi = gate_lds[0][tid], gf = gate_lds[1][tid];
        float gc = gate_lds[2][tid], go = gate_lds[3][tid];
        float cc = chpn_sigmoid(gf) * c_st[tid * kNH + j] + chpn_sigmoid(gi) * chpn_tanh(gc);
        float hh = chpn_sigmoid(go) * chpn_tanh(cc);
        c_st[tid * kNH + j] = cc;
        h_dst[tid * kNH + j] = hh;
    }
}

__global__ __launch_bounds__(256) void fb_query(
    const float* __restrict__ wqT, const float* __restrict__ h_src,
    float* __restrict__ query, float* __restrict__ ctx_num,
    float* __restrict__ denom)
{
    __shared__ float hl[kNH];
    __shared__ float partq[256];
    int bid = blockIdx.x;
    int bb = bid >> 2, hc = bid & 3;
    int tid = threadIdx.x;
    hl[tid] = h_src[bb * kNH + tid];
    hl[tid + 256] = h_src[bb * kNH + tid + 256];
    __syncthreads();
    int h = hc * 128 + (tid & 127);
    int jh = tid >> 7;
    float acc = 0.f;
    const float* wcol = wqT + h;
    #pragma unroll 8
    for (int j = jh * 256; j < jh * 256 + 256; ++j)
        acc = fmaf(hl[j], wcol[(size_t)j * kNH], acc);
    partq[tid] = acc;
    __syncthreads();
    if (tid < 128) {
        float q = partq[tid] + partq[tid + 128];
        query[bb * kNH + h] = q;
        ctx_num[bb * kNH + h] = 0.0f;
        if (hc == 0 && tid == 0) denom[bb] = 0.0f;
    }
}

__global__ __launch_bounds__(1024) void fb_score_ctx(
    const chpn_f16* __restrict__ keysT, const chpn_f16* __restrict__ enc_outs,
    const float* __restrict__ query, const float* __restrict__ vvec,
    float* __restrict__ ctx_num, float* __restrict__ denom,
    float* __restrict__ out, int t)
{
    __shared__ float ql[kNH], vl[kNH];
    __shared__ float part[16][64];
    __shared__ float el[64];
    int bid = blockIdx.x;
    int bb = bid >> 3, sc = bid & 7;
    int s0 = sc * 64;
    int tid = threadIdx.x;
    int s = tid & 63, hq = tid >> 6;
    if (tid < kNH) { ql[tid] = query[bb * kNH + tid]; vl[tid] = vvec[tid]; }
    __syncthreads();
    float acc = 0.f;
    const chpn_f16* kp = keysT + (size_t)bb * kNH * kNS + s0 + s;
    const int h0 = hq * 32;
    #pragma unroll 4
    for (int h = h0; h < h0 + 32; ++h) {
        float kv = (float)kp[(size_t)h * kNS];
        acc = fmaf(vl[h], chpn_tanh(ql[h] + kv), acc);
    }
    part[hq][s] = acc;
    __syncthreads();
    if (tid < 64) {
        float scv = 0.f;
        #pragma unroll
        for (int q = 0; q < 16; ++q) scv += part[q][tid];
        out[((size_t)bb * kNT + t) * kNS + s0 + tid] = scv;
        float e = __expf(scv);
        el[tid] = e;
        float wsum = e;
        #pragma unroll
        for (int off = 32; off > 0; off >>= 1) wsum += __shfl_down(wsum, off);
        if (tid == 0) atomicAdd(&denom[bb], wsum);
    }
    __syncthreads();
    int j = tid & 511, sh = tid >> 9;
    float a = 0.f;
    const chpn_f16* ep = enc_outs + ((size_t)bb * kNS + s0 + sh * 32) * kNH + j;
    #pragma unroll 4
    for (int ss = 0; ss < 32; ++ss)
        a = fmaf(el[sh * 32 + ss], (float)ep[(size_t)ss * kNH], a);
    atomicAdd(&ctx_num[bb * kNH + j], a);
}

extern "C" void kernel_launch(void* const* d_in, const int* in_sizes, int n_in,
                              void* d_out, int out_size, void* d_ws, size_t ws_size,
                              hipStream_t stream) {
    const float* inputs = (const float*)d_in[0];
    const float* e_wih  = (const float*)d_in[1];
    const float* e_whh  = (const float*)d_in[2];
    const float* e_bih  = (const float*)d_in[3];
    const float* e_bhh  = (const float*)d_in[4];
    const float* d_wih  = (const float*)d_in[5];
    const float* d_whh  = (const float*)d_in[6];
    const float* d_bih  = (const float*)d_in[7];
    const float* d_bhh  = (const float*)d_in[8];
    const float* w_key  = (const float*)d_in[9];
    const float* w_qry  = (const float*)d_in[10];
    const float* v_vec  = (const float*)d_in[11];
    float* out = (float*)d_out;               // f32 output (64 MB)

    float* wsf   = (float*)d_ws;
    float* h0    = wsf;
    float* cst   = h0 + kNB * kNH;
    float* h1    = cst + kNB * kNH;
    float* query = h1 + kNB * kNH;
    float* ctxn  = query + kNB * kNH;
    float* denom = ctxn + kNB * kNH;
    float* encb  = denom + 64;
    float* decb  = encb + kNG;
    float* wqT   = decb + kNG;
    chpn_f16* keysH = (chpn_f16*)(wqT + (size_t)kNH * kNH);   // 33.5 MB
    chpn_f16* encH  = keysH + (size_t)kNB * kNH * kNS;        // 33.5 MB

    ConvexHullPointerNetwork_57303453663418_kernel<<<1024, 256, 0, stream>>>(
        e_bih, e_bhh, d_bih, d_bhh, w_qry, encb, decb, wqT, h0);

    {   // encoder loop (cooperative; fallback to per-step on enqueue error)
        void* args[] = { (void*)&inputs, (void*)&e_wih, (void*)&e_whh,
                         (void*)&encb, (void*)&h0, (void*)&h1,
                         (void*)&cst, (void*)&encH };
        hipError_t rc = hipLaunchCooperativeKernel((const void*)chpn_enc_loop,
                                                   dim3(256), dim3(1024),
                                                   args, 0, stream);
        if (rc != hipSuccess) {
            (void)hipGetLastError();
            for (int t = 0; t < kNS; ++t) {
                float* hs = (t & 1) ? h1 : h0;
                float* hd = (t & 1) ? h0 : h1;
                fb_enc_cell<<<512, 256, 0, stream>>>(inputs, e_wih, e_whh, encb,
                                                     hs, hd, cst, encH, t);
            }
        }
    }

    chpn_keys_gemm<<<4096, 256, 0, stream>>>(encH, w_key, keysH);

    {   // decoder loop (cooperative; fallback on enqueue error)
        void* args[] = { (void*)&d_wih, (void*)&d_whh, (void*)&decb,
                         (void*)&wqT, (void*)&v_vec, (void*)&keysH,
                         (void*)&encH, (void*)&h0, (void*)&h1, (void*)&cst,
                         (void*)&query, (void*)&ctxn, (void*)&denom,
                         (void*)&out };
        hipError_t rc = hipLaunchCooperativeKernel((const void*)chpn_dec_loop,
                                                   dim3(256), dim3(1024),
                                                   args, 0, stream);
        if (rc != hipSuccess) {
            (void)hipGetLastError();
            for (int t = 0; t < kNT; ++t) {
                float* hs = (t & 1) ? h1 : h0;
                float* hd = (t & 1) ? h0 : h1;
                fb_dec_cell<<<512, 256, 0, stream>>>(d_wih, d_whh, decb,
                                                     hs, hd, cst,
                                                     ctxn, denom, t == 0 ? 1 : 0);
                fb_query<<<256, 256, 0, stream>>>(wqT, hd, query, ctxn, denom);
                fb_score_ctx<<<512, 1024, 0, stream>>>(keysH, encH, query, v_vec,
                                                       ctxn, denom, out, t);
            }
        }
    }
}